// Round 6
// baseline (260.660 us; speedup 1.0000x reference)
//
#include <hip/hip_runtime.h>
#include <stdint.h>

typedef unsigned short u16;
typedef __bf16 bf16x8 __attribute__((ext_vector_type(8)));
typedef float f32x4 __attribute__((ext_vector_type(4)));
typedef float f32x16 __attribute__((ext_vector_type(16)));
typedef unsigned u32x4 __attribute__((ext_vector_type(4)));

#define DEVI __device__ __forceinline__

typedef __attribute__((address_space(1))) void gvoid;
typedef __attribute__((address_space(3))) void lvoid;

template<int N> struct IC { static constexpr int v = N; };

DEVI u16 f2b(float f) {
  unsigned x = __builtin_bit_cast(unsigned, f);
  return (u16)((x + 0x7fffu + ((x >> 16) & 1u)) >> 16);
}

DEVI float exp2g(float x) { return __builtin_amdgcn_exp2f(x); }

DEVI void gload_lds16(const void* g, void* l) {
  __builtin_amdgcn_global_load_lds((gvoid*)g, (lvoid*)l, 16, 0, 0);
}

// ---------------------------------------------------------------- cast kernels
// Q rows of w_qkv get scale 0.125 * log2(e): folds the attention 1/8 scale AND
// the exp->exp2 conversion into the QKV GEMM.
#define QSCALE 0.18033688011112042f

__global__ void cast_x(const float* __restrict__ in, u16* __restrict__ out, int n4) {
  int i = blockIdx.x * 256 + threadIdx.x;
  int stride = gridDim.x * 256;
  for (; i < n4; i += stride) {
    float4 v = ((const float4*)in)[i];
    ushort4 o;
    o.x = f2b(v.x); o.y = f2b(v.y); o.z = f2b(v.z); o.w = f2b(v.w);
    ((ushort4*)out)[i] = o;
  }
}

__global__ void cast_w(const float* __restrict__ wqkv, const float* __restrict__ wout,
                       u16* __restrict__ outb) {
  int i = blockIdx.x * 256 + threadIdx.x;
  int stride = gridDim.x * 256;
  for (; i < 1048576; i += stride) {
    const float* src = (i < 786432) ? wqkv + 4 * (long)i : wout + 4 * (long)(i - 786432);
    float4 v = *(const float4*)src;
    if (i < 262144) { v.x *= QSCALE; v.y *= QSCALE; v.z *= QSCALE; v.w *= QSCALE; }
    ushort4 o;
    o.x = f2b(v.x); o.y = f2b(v.y); o.z = f2b(v.z); o.w = f2b(v.w);
    ((ushort4*)outb)[i] = o;
  }
}

// ---------------------------------------------------------------- GEMM C = A * B^T
template<bool BF16OUT>
__global__ __launch_bounds__(256)
void gemm_bt(const u16* __restrict__ A, const u16* __restrict__ B, void* __restrict__ Cv,
             int M, int N, int K) {
  __shared__ u16 lA[128 * 64];
  __shared__ u16 lB[128 * 64];
  const int tid = threadIdx.x;
  const int lane = tid & 63;
  const int lr = lane & 15;
  const int lg = lane >> 4;
  const int wid = tid >> 6;
  const long bm = (long)blockIdx.y * 128;
  const long bn = (long)blockIdx.x * 128;
  const int wr = (wid >> 1) * 64;
  const int wc = (wid & 1) * 64;

  f32x4 acc[4][4];
#pragma unroll
  for (int i = 0; i < 4; ++i)
#pragma unroll
    for (int j = 0; j < 4; ++j)
      acc[i][j] = (f32x4){0.f, 0.f, 0.f, 0.f};

  for (int k0 = 0; k0 < K; k0 += 64) {
#pragma unroll
    for (int q = 0; q < 4; ++q) {
      int bi = tid + q * 256;
      int row = bi >> 3;
      int col = ((bi & 7) ^ (row & 7)) * 8;
      gload_lds16(A + (bm + row) * (long)K + k0 + col, (char*)lA + bi * 16);
    }
#pragma unroll
    for (int q = 0; q < 4; ++q) {
      int bi = tid + q * 256;
      int row = bi >> 3;
      int col = ((bi & 7) ^ (row & 7)) * 8;
      gload_lds16(B + (bn + row) * (long)K + k0 + col, (char*)lB + bi * 16);
    }
    __syncthreads();
#pragma unroll
    for (int kk = 0; kk < 2; ++kk) {
      bf16x8 af[4], bfr[4];
      int kb = kk * 4 + lg;
#pragma unroll
      for (int mi = 0; mi < 4; ++mi) {
        int row = wr + mi * 16 + lr;
        af[mi] = *(const bf16x8*)((const char*)lA + row * 128 + ((kb ^ (row & 7)) << 4));
      }
#pragma unroll
      for (int ni = 0; ni < 4; ++ni) {
        int row = wc + ni * 16 + lr;
        bfr[ni] = *(const bf16x8*)((const char*)lB + row * 128 + ((kb ^ (row & 7)) << 4));
      }
#pragma unroll
      for (int mi = 0; mi < 4; ++mi)
#pragma unroll
        for (int ni = 0; ni < 4; ++ni)
          acc[mi][ni] = __builtin_amdgcn_mfma_f32_16x16x32_bf16(af[mi], bfr[ni], acc[mi][ni], 0, 0, 0);
    }
    __syncthreads();
  }
#pragma unroll
  for (int mi = 0; mi < 4; ++mi)
#pragma unroll
    for (int ni = 0; ni < 4; ++ni)
#pragma unroll
      for (int r = 0; r < 4; ++r) {
        long row = bm + wr + mi * 16 + lg * 4 + r;
        long col = bn + wc + ni * 16 + lr;
        float v = acc[mi][ni][r];
        if (BF16OUT) ((u16*)Cv)[row * (long)N + col] = f2b(v);
        else         ((float*)Cv)[row * (long)N + col] = v;
      }
}

// ---------------------------------------------------------------- flash attention v5
// = v4 (32x32x16 swapped MFMA, skip-max exp2 softmax, in-register P via
// permlane32_swap) + depth-2 prefetch with counted-vmcnt raw barriers (T3/T4):
// 4 K LDS buffers (gload_lds), 2 V LDS buffers + 2 V register sets (T14).
// Waves 0-3: end-of-tile s_waitcnt vmcnt(2) (never 0) -> 2 K-tiles in flight
// across barriers. Waves 4-7: lgkmcnt(0) for V ds_writes. Loop unrolled x4 so
// all buffer indices are compile-time.
__global__ __launch_bounds__(512, 4)
void attn_fwd(const u16* __restrict__ qkv, u16* __restrict__ outb) {
  __shared__ char SM[49152];   // K bufs: 4 x 8KB @0; V bufs: 2 x 8KB @32768

  const int tid = threadIdx.x;
  const int lane = tid & 63;
  const int wid = tid >> 6;
  const int ql = lane & 31;
  const int h  = lane >> 5;
  const int th = wid >> 2;     // t-half: waves 0-3 -> t 0..31, waves 4-7 -> 32..63
  const int qb = wid & 3;
  const int qt = blockIdx.x;
  const int hd = blockIdx.y;
  const int b  = blockIdx.z;

  const long rowbase = (long)b * 2048;
  const int qcol = hd * 64;
  const int kcol = 1024 + hd * 64;
  const int vcol = 2048 + hd * 64;
  const int TS = 64 * 3072;    // elements per t-tile stride

  const int q0w = qt * 128 + qb * 32;
  bf16x8 qf[4];
  {
    const u16* qp = qkv + (rowbase + q0w + ql) * 3072 + qcol + h * 8;
#pragma unroll
    for (int dblk = 0; dblk < 4; ++dblk)
      qf[dblk] = *(const bf16x8*)(qp + dblk * 16);
  }

  float l_r = 0.f;
  f32x16 o[2];
#pragma unroll
  for (int d = 0; d < 2; ++d)
#pragma unroll
    for (int r = 0; r < 16; ++r) o[d][r] = 0.f;

  // ---- staging descriptors
  // waves 0-3: two 16B K chunks per tile via gload_lds (pre-swizzled source)
  const int t_a = tid >> 3,           c_a = ((tid & 7) ^ (t_a & 7)) * 8;
  const int bi1 = tid + 256;
  const int t_b = bi1 >> 3,           c_b = ((bi1 & 7) ^ (t_b & 7)) * 8;
  const int d0b = tid * 16, d1b = bi1 * 16;
  const u16* kp0;
  const u16* kp1;
  // waves 4-7: V rows vtl, vtl+1 at cols vd0..vd0+7; two register sets
  const int vv = tid - 256;
  const int vtl = (vv & 31) * 2;
  const int vd0 = ((vv >> 5) & 7) * 8;
  const u16* vp;
  uint4 vA0, vA1, vB0, vB1;

  auto VWRITE = [&](char* dst, uint4 a, uint4 b) {
    const unsigned* aw = (const unsigned*)&a;
    const unsigned* bw = (const unsigned*)&b;
#pragma unroll
    for (int jj = 0; jj < 8; ++jj) {
      unsigned val = __builtin_amdgcn_perm(bw[jj >> 1], aw[jj >> 1],
                                           (jj & 1) ? 0x07060302u : 0x05040100u);
      int d = vd0 + jj;
      *(unsigned*)(dst + ((d * 128 + vtl * 2) ^ ((d & 7) << 4))) = val;
    }
  };

  // ---- prologue: stage tiles 0 and 1
  if (tid < 256) {
    kp0 = qkv + (rowbase + t_a) * 3072 + kcol + c_a;
    kp1 = qkv + (rowbase + t_b) * 3072 + kcol + c_b;
    gload_lds16(kp0, SM + d0b);          gload_lds16(kp1, SM + d1b);
    gload_lds16(kp0 + TS, SM + 8192 + d0b); gload_lds16(kp1 + TS, SM + 8192 + d1b);
    kp0 += 2 * TS; kp1 += 2 * TS;
  } else {
    vp = qkv + (rowbase + vtl) * 3072 + vcol + vd0;
    vA0 = *(const uint4*)vp; vA1 = *(const uint4*)(vp + 3072); vp += TS;
    vB0 = *(const uint4*)vp; vB1 = *(const uint4*)(vp + 3072); vp += TS;
    VWRITE(SM + 32768, vA0, vA1);
  }
  if (tid < 256) asm volatile("s_waitcnt vmcnt(2)" ::: "memory");
  else           asm volatile("s_waitcnt lgkmcnt(0)" ::: "memory");
  __builtin_amdgcn_s_barrier();
  __builtin_amdgcn_sched_barrier(0);

  // ---- main loop, unrolled x4 (I = tile index mod 4)
  auto body = [&](auto icv) {
    constexpr int I = decltype(icv)::v;
    char* KsCur = SM + I * 8192;
    char* KsNxt = SM + ((I + 2) & 3) * 8192;
    char* VsCur = SM + 32768 + (I & 1) * 8192;
    char* VsWr  = SM + 32768 + ((I + 1) & 1) * 8192;

    // stage issue for tile t+2 (wrapped loads at tail are harmless)
    if (tid < 256) {
      gload_lds16(kp0, KsNxt + d0b);
      gload_lds16(kp1, KsNxt + d1b);
      kp0 += TS; kp1 += TS;
    } else {
      if constexpr (I & 1) { vB0 = *(const uint4*)vp; vB1 = *(const uint4*)(vp + 3072); }
      else                 { vA0 = *(const uint4*)vp; vA1 = *(const uint4*)(vp + 3072); }
      vp += TS;
    }

    // ---- S^T = K Q^T
    f32x16 s;
#pragma unroll
    for (int r = 0; r < 16; ++r) s[r] = 0.f;
    const char* Kb = KsCur + (th * 32 + ql) * 128;
    __builtin_amdgcn_s_setprio(1);
#pragma unroll
    for (int kd = 0; kd < 4; ++kd) {
      bf16x8 kf = *(const bf16x8*)(Kb + (((kd * 2 + h) ^ (ql & 7)) << 4));
      s = __builtin_amdgcn_mfma_f32_32x32x16_bf16(kf, qf[kd], s, 0, 0, 0);
    }
    __builtin_amdgcn_s_setprio(0);

    // ---- late V write for tile t+1 (loads issued last body; T14)
    if (tid >= 256) {
      if constexpr (I & 1) VWRITE(VsWr, vA0, vA1);
      else                 VWRITE(VsWr, vB0, vB1);
    }

    // ---- softmax (shift=0): p = exp2(s), in place
#pragma unroll
    for (int r = 0; r < 16; ++r) s[r] = exp2g(s[r]);
    l_r += (((s[0] + s[1]) + (s[2] + s[3])) + ((s[4] + s[5]) + (s[6] + s[7])))
         + (((s[8] + s[9]) + (s[10] + s[11])) + ((s[12] + s[13]) + (s[14] + s[15])));

    unsigned w[8];
#pragma unroll
    for (int m = 0; m < 8; ++m)
      asm("v_cvt_pk_bf16_f32 %0, %1, %2" : "=v"(w[m]) : "v"(s[2 * m]), "v"(s[2 * m + 1]));

    bf16x8 pb[2];
#pragma unroll
    for (int ks = 0; ks < 2; ++ks) {
      unsigned a0 = w[4 * ks],     a2 = w[4 * ks + 2];
      unsigned a1 = w[4 * ks + 1], a3 = w[4 * ks + 3];
      asm("s_nop 1\n\tv_permlane32_swap_b32 %0, %1" : "+v"(a0), "+v"(a2));
      asm("s_nop 1\n\tv_permlane32_swap_b32 %0, %1" : "+v"(a1), "+v"(a3));
      u32x4 t; t[0] = a0; t[1] = a1; t[2] = a2; t[3] = a3;
      pb[ks] = __builtin_bit_cast(bf16x8, t);
    }

    // ---- O^T += V^T P^T
    __builtin_amdgcn_s_setprio(1);
#pragma unroll
    for (int dblk = 0; dblk < 2; ++dblk) {
      const char* Vb = VsCur + (dblk * 32 + ql) * 128;
#pragma unroll
      for (int ks = 0; ks < 2; ++ks) {
        bf16x8 vf = *(const bf16x8*)(Vb + (((th * 4 + ks * 2 + h) ^ (ql & 7)) << 4));
        o[dblk] = __builtin_amdgcn_mfma_f32_32x32x16_bf16(vf, pb[ks], o[dblk], 0, 0, 0);
      }
    }
    __builtin_amdgcn_s_setprio(0);

    // ---- counted-wait barrier: K tile t+1 guaranteed landed; never vmcnt(0)
    if (tid < 256) asm volatile("s_waitcnt vmcnt(2)" ::: "memory");
    else           asm volatile("s_waitcnt lgkmcnt(0)" ::: "memory");
    __builtin_amdgcn_s_barrier();
    __builtin_amdgcn_sched_barrier(0);
  };

  for (int base = 0; base < 32; base += 4) {
    body(IC<0>{}); body(IC<1>{}); body(IC<2>{}); body(IC<3>{});
  }

  // drain the tail wrapped K loads before reusing SM for the epilogue
  if (tid < 256) asm volatile("s_waitcnt vmcnt(0)" ::: "memory");
  __syncthreads();

  // ---- cross-half l sum (lane l <-> l^32 hold complementary t-subsets)
  float px = l_r, py = l_r;
  asm("s_nop 1\n\tv_permlane32_swap_b32 %0, %1" : "+v"(px), "+v"(py));
  float lw = l_r + (h ? px : py);

  // ---- epilogue combine across t-halves (wave pairs w, w+4 share qb)
  if (th == 1) {
    char* reg = SM + qb * 8320;
#pragma unroll
    for (int dblk = 0; dblk < 2; ++dblk)
#pragma unroll
      for (int r = 0; r < 16; ++r) {
        int dl = dblk * 32 + (r & 3) + 8 * (r >> 2) + 4 * h;
        *(float*)(reg + dl * 128 + ql * 4) = o[dblk][r];
      }
    if (h == 0) *(float*)(reg + 8192 + ql * 4) = lw;
  }
  __syncthreads();
  if (th == 0) {
    const char* reg = SM + qb * 8320;
#pragma unroll
    for (int dblk = 0; dblk < 2; ++dblk)
#pragma unroll
      for (int r = 0; r < 16; ++r) {
        int dl = dblk * 32 + (r & 3) + 8 * (r >> 2) + 4 * h;
        o[dblk][r] += *(const float*)(reg + dl * 128 + ql * 4);
      }
    float inv = 1.0f / (lw + *(const float*)(reg + 8192 + ql * 4));
    long row = rowbase + q0w + ql;
#pragma unroll
    for (int dblk = 0; dblk < 2; ++dblk)
#pragma unroll
      for (int m = 0; m < 4; ++m) {
        ushort4 st;
        st.x = f2b(o[dblk][4 * m + 0] * inv);
        st.y = f2b(o[dblk][4 * m + 1] * inv);
        st.z = f2b(o[dblk][4 * m + 2] * inv);
        st.w = f2b(o[dblk][4 * m + 3] * inv);
        *(ushort4*)(outb + row * 1024 + qcol + dblk * 32 + 8 * m + 4 * h) = st;
      }
  }
}

// ---------------------------------------------------------------- launch
extern "C" void kernel_launch(void* const* d_in, const int* in_sizes, int n_in,
                              void* d_out, int out_size, void* d_ws, size_t ws_size,
                              hipStream_t stream) {
  const float* x     = (const float*)d_in[0];  // [2,2048,1024]
  const float* w_qkv = (const float*)d_in[1];  // [3072,1024]
  const float* w_out = (const float*)d_in[2];  // [1024,1024]
  float* out = (float*)d_out;                  // [2,2048,1024] fp32

  char* ws = (char*)d_ws;
  u16* xb    = (u16*)(ws);                     //  8 MB
  u16* wqkvb = (u16*)(ws + 8388608);           //  6 MB (w_out cast follows contiguously)
  u16* woutb = (u16*)(ws + 14680064);          //  2 MB
  u16* qkv   = (u16*)(ws + 16777216);          // 24 MB
  u16* attn  = (u16*)(ws + 41943040);          //  8 MB

  cast_x<<<1024, 256, 0, stream>>>(x, xb, 4096 * 1024 / 4);
  cast_w<<<1024, 256, 0, stream>>>(w_qkv, w_out, wqkvb);

  gemm_bt<true ><<<dim3(24, 32), 256, 0, stream>>>(xb, wqkvb, qkv, 4096, 3072, 1024);
  attn_fwd<<<dim3(16, 16, 2), 512, 0, stream>>>(qkv, attn);
  gemm_bt<false><<<dim3(8, 32), 256, 0, stream>>>(attn, woutb, out, 4096, 1024, 1024);
}

// Round 7
// 235.791 us; speedup vs baseline: 1.1055x; 1.1055x over previous
//
#include <hip/hip_runtime.h>
#include <stdint.h>

typedef unsigned short u16;
typedef __bf16 bf16x8 __attribute__((ext_vector_type(8)));
typedef float f32x4 __attribute__((ext_vector_type(4)));
typedef float f32x16 __attribute__((ext_vector_type(16)));
typedef unsigned u32x4 __attribute__((ext_vector_type(4)));

#define DEVI __device__ __forceinline__

typedef __attribute__((address_space(1))) void gvoid;
typedef __attribute__((address_space(3))) void lvoid;

DEVI u16 f2b(float f) {
  unsigned x = __builtin_bit_cast(unsigned, f);
  return (u16)((x + 0x7fffu + ((x >> 16) & 1u)) >> 16);
}

DEVI float exp2g(float x) { return __builtin_amdgcn_exp2f(x); }

DEVI void gload_lds16(const void* g, void* l) {
  __builtin_amdgcn_global_load_lds((gvoid*)g, (lvoid*)l, 16, 0, 0);
}

// ---------------------------------------------------------------- cast kernels
// Q rows of w_qkv get scale 0.125 * log2(e): folds the attention 1/8 scale AND
// the exp->exp2 conversion into the QKV GEMM.
#define QSCALE 0.18033688011112042f

__global__ void cast_x(const float* __restrict__ in, u16* __restrict__ out, int n4) {
  int i = blockIdx.x * 256 + threadIdx.x;
  int stride = gridDim.x * 256;
  for (; i < n4; i += stride) {
    float4 v = ((const float4*)in)[i];
    ushort4 o;
    o.x = f2b(v.x); o.y = f2b(v.y); o.z = f2b(v.z); o.w = f2b(v.w);
    ((ushort4*)out)[i] = o;
  }
}

__global__ void cast_w(const float* __restrict__ wqkv, const float* __restrict__ wout,
                       u16* __restrict__ outb) {
  int i = blockIdx.x * 256 + threadIdx.x;
  int stride = gridDim.x * 256;
  for (; i < 1048576; i += stride) {
    const float* src = (i < 786432) ? wqkv + 4 * (long)i : wout + 4 * (long)(i - 786432);
    float4 v = *(const float4*)src;
    if (i < 262144) { v.x *= QSCALE; v.y *= QSCALE; v.z *= QSCALE; v.w *= QSCALE; }
    ushort4 o;
    o.x = f2b(v.x); o.y = f2b(v.y); o.z = f2b(v.z); o.w = f2b(v.w);
    ((ushort4*)outb)[i] = o;
  }
}

// ---------------------------------------------------------------- GEMM C = A * B^T
template<bool BF16OUT>
__global__ __launch_bounds__(256)
void gemm_bt(const u16* __restrict__ A, const u16* __restrict__ B, void* __restrict__ Cv,
             int M, int N, int K) {
  __shared__ u16 lA[128 * 64];
  __shared__ u16 lB[128 * 64];
  const int tid = threadIdx.x;
  const int lane = tid & 63;
  const int lr = lane & 15;
  const int lg = lane >> 4;
  const int wid = tid >> 6;
  const long bm = (long)blockIdx.y * 128;
  const long bn = (long)blockIdx.x * 128;
  const int wr = (wid >> 1) * 64;
  const int wc = (wid & 1) * 64;

  f32x4 acc[4][4];
#pragma unroll
  for (int i = 0; i < 4; ++i)
#pragma unroll
    for (int j = 0; j < 4; ++j)
      acc[i][j] = (f32x4){0.f, 0.f, 0.f, 0.f};

  for (int k0 = 0; k0 < K; k0 += 64) {
#pragma unroll
    for (int q = 0; q < 4; ++q) {
      int bi = tid + q * 256;
      int row = bi >> 3;
      int col = ((bi & 7) ^ (row & 7)) * 8;
      gload_lds16(A + (bm + row) * (long)K + k0 + col, (char*)lA + bi * 16);
    }
#pragma unroll
    for (int q = 0; q < 4; ++q) {
      int bi = tid + q * 256;
      int row = bi >> 3;
      int col = ((bi & 7) ^ (row & 7)) * 8;
      gload_lds16(B + (bn + row) * (long)K + k0 + col, (char*)lB + bi * 16);
    }
    __syncthreads();
#pragma unroll
    for (int kk = 0; kk < 2; ++kk) {
      bf16x8 af[4], bfr[4];
      int kb = kk * 4 + lg;
#pragma unroll
      for (int mi = 0; mi < 4; ++mi) {
        int row = wr + mi * 16 + lr;
        af[mi] = *(const bf16x8*)((const char*)lA + row * 128 + ((kb ^ (row & 7)) << 4));
      }
#pragma unroll
      for (int ni = 0; ni < 4; ++ni) {
        int row = wc + ni * 16 + lr;
        bfr[ni] = *(const bf16x8*)((const char*)lB + row * 128 + ((kb ^ (row & 7)) << 4));
      }
#pragma unroll
      for (int mi = 0; mi < 4; ++mi)
#pragma unroll
        for (int ni = 0; ni < 4; ++ni)
          acc[mi][ni] = __builtin_amdgcn_mfma_f32_16x16x32_bf16(af[mi], bfr[ni], acc[mi][ni], 0, 0, 0);
    }
    __syncthreads();
  }
#pragma unroll
  for (int mi = 0; mi < 4; ++mi)
#pragma unroll
    for (int ni = 0; ni < 4; ++ni)
#pragma unroll
      for (int r = 0; r < 4; ++r) {
        long row = bm + wr + mi * 16 + lg * 4 + r;
        long col = bn + wc + ni * 16 + lr;
        float v = acc[mi][ni][r];
        if (BF16OUT) ((u16*)Cv)[row * (long)N + col] = f2b(v);
        else         ((float*)Cv)[row * (long)N + col] = v;
      }
}

// ---------------------------------------------------------------- flash attention v6
// v4 math (32x32x16 swapped MFMA, skip-max exp2 softmax, in-register P via
// permlane32_swap) + counted-vmcnt raw barriers with depth-2 K prefetch.
// FLAT code: no lambdas (v5's capture materialization caused scratch spill),
// inner I=0..3 loop fully unrolled so all LDS buffer offsets are compile-time.
// K: 4 LDS bufs via gload_lds, issued 2 tiles ahead; waves 0-3 end each tile
// with s_waitcnt vmcnt(2) (never 0). V: single reg set, load top / write late
// (T14), 2 LDS bufs; waves 4-7 end with lgkmcnt(0). One barrier per tile.
__global__ __launch_bounds__(512, 4)
void attn_fwd(const u16* __restrict__ qkv, u16* __restrict__ outb) {
  __shared__ char SM[49152];   // K bufs: 4 x 8KB @0; V bufs: 2 x 8KB @32768

  const int tid = threadIdx.x;
  const int lane = tid & 63;
  const int wid = tid >> 6;
  const int ql = lane & 31;
  const int h  = lane >> 5;
  const int th = wid >> 2;     // t-half: waves 0-3 -> t 0..31, waves 4-7 -> 32..63
  const int qb = wid & 3;
  const int qt = blockIdx.x;
  const int hd = blockIdx.y;
  const int b  = blockIdx.z;

  const long rowbase = (long)b * 2048;
  const int qcol = hd * 64;
  const int kcol = 1024 + hd * 64;
  const int vcol = 2048 + hd * 64;
  const int TS = 64 * 3072;    // elements per t-tile stride

  const int q0w = qt * 128 + qb * 32;
  bf16x8 qf[4];
  {
    const u16* qp = qkv + (rowbase + q0w + ql) * 3072 + qcol + h * 8;
#pragma unroll
    for (int dblk = 0; dblk < 4; ++dblk)
      qf[dblk] = *(const bf16x8*)(qp + dblk * 16);
  }

  float l_r = 0.f;
  f32x16 o[2];
#pragma unroll
  for (int d = 0; d < 2; ++d)
#pragma unroll
    for (int r = 0; r < 16; ++r) o[d][r] = 0.f;

  // K staging addresses (waves 0-3): two 16B chunks per tile, pre-swizzled src
  const int t_a = tid >> 3,  c_a = ((tid & 7) ^ (t_a & 7)) * 8;
  const int bi1 = (tid & 255) + 256;
  const int t_b = bi1 >> 3,  c_b = ((bi1 & 7) ^ (t_b & 7)) * 8;
  const int d0b = (tid & 255) * 16, d1b = bi1 * 16;
  // V staging (waves 4-7): rows vtl, vtl+1, cols vd0..vd0+7, single reg set
  const int vv = tid & 255;
  const int vtl = (vv & 31) * 2;
  const int vd0 = ((vv >> 5) & 7) * 8;
  const u16* kp0 = qkv + (rowbase + t_a) * 3072 + kcol + c_a;
  const u16* kp1 = qkv + (rowbase + t_b) * 3072 + kcol + c_b;
  const u16* vp  = qkv + (rowbase + vtl) * 3072 + vcol + vd0;
  uint4 va0, va1;

  // ---- prologue: K[0]->buf0, K[1]->buf1; V[0]->regs->Vs0
  if (tid < 256) {
    gload_lds16(kp0, SM + d0b);             gload_lds16(kp1, SM + d1b);
    gload_lds16(kp0 + TS, SM + 8192 + d0b); gload_lds16(kp1 + TS, SM + 8192 + d1b);
    kp0 += 2 * TS; kp1 += 2 * TS;
    asm volatile("s_waitcnt vmcnt(2)" ::: "memory");
  } else {
    va0 = *(const uint4*)vp; va1 = *(const uint4*)(vp + 3072); vp += TS;
    {
      const unsigned* aw = (const unsigned*)&va0;
      const unsigned* bw = (const unsigned*)&va1;
#pragma unroll
      for (int jj = 0; jj < 8; ++jj) {
        unsigned val = __builtin_amdgcn_perm(bw[jj >> 1], aw[jj >> 1],
                                             (jj & 1) ? 0x07060302u : 0x05040100u);
        int d = vd0 + jj;
        *(unsigned*)(SM + 32768 + ((d * 128 + vtl * 2) ^ ((d & 7) << 4))) = val;
      }
    }
    asm volatile("s_waitcnt lgkmcnt(0)" ::: "memory");
  }
  __builtin_amdgcn_s_barrier();
  __builtin_amdgcn_sched_barrier(0);

  // ---- main loop: 8 outer x 4 unrolled = 32 tiles
  for (int tt = 0; tt < 8; ++tt) {
#pragma unroll
    for (int I = 0; I < 4; ++I) {
      char* KsCur = SM + I * 8192;
      char* KsNxt = SM + ((I + 2) & 3) * 8192;
      char* VsCur = SM + 32768 + (I & 1) * 8192;
      char* VsWr  = SM + 32768 + ((I + 1) & 1) * 8192;

      // stage issue: K[t+2] via gload_lds; V[t+1] global->reg (wrapped at tail)
      if (tid < 256) {
        gload_lds16(kp0, KsNxt + d0b);
        gload_lds16(kp1, KsNxt + d1b);
        kp0 += TS; kp1 += TS;
      } else {
        va0 = *(const uint4*)vp; va1 = *(const uint4*)(vp + 3072); vp += TS;
      }

      // ---- S^T = K Q^T
      f32x16 s;
#pragma unroll
      for (int r = 0; r < 16; ++r) s[r] = 0.f;
      const char* Kb = KsCur + (th * 32 + ql) * 128;
      __builtin_amdgcn_s_setprio(1);
#pragma unroll
      for (int kd = 0; kd < 4; ++kd) {
        bf16x8 kf = *(const bf16x8*)(Kb + (((kd * 2 + h) ^ (ql & 7)) << 4));
        s = __builtin_amdgcn_mfma_f32_32x32x16_bf16(kf, qf[kd], s, 0, 0, 0);
      }
      __builtin_amdgcn_s_setprio(0);

      // ---- late V write for tile t+1 (T14; implicit vmcnt wait on va regs)
      if (tid >= 256) {
        const unsigned* aw = (const unsigned*)&va0;
        const unsigned* bw = (const unsigned*)&va1;
#pragma unroll
        for (int jj = 0; jj < 8; ++jj) {
          unsigned val = __builtin_amdgcn_perm(bw[jj >> 1], aw[jj >> 1],
                                               (jj & 1) ? 0x07060302u : 0x05040100u);
          int d = vd0 + jj;
          *(unsigned*)(VsWr + ((d * 128 + vtl * 2) ^ ((d & 7) << 4))) = val;
        }
      }

      // ---- softmax (shift=0): p = exp2(s) in place
#pragma unroll
      for (int r = 0; r < 16; ++r) s[r] = exp2g(s[r]);
      l_r += (((s[0] + s[1]) + (s[2] + s[3])) + ((s[4] + s[5]) + (s[6] + s[7])))
           + (((s[8] + s[9]) + (s[10] + s[11])) + ((s[12] + s[13]) + (s[14] + s[15])));

      unsigned w[8];
#pragma unroll
      for (int m = 0; m < 8; ++m)
        asm("v_cvt_pk_bf16_f32 %0, %1, %2" : "=v"(w[m]) : "v"(s[2 * m]), "v"(s[2 * m + 1]));

      bf16x8 pb[2];
#pragma unroll
      for (int ks = 0; ks < 2; ++ks) {
        unsigned a0 = w[4 * ks],     a2 = w[4 * ks + 2];
        unsigned a1 = w[4 * ks + 1], a3 = w[4 * ks + 3];
        asm("s_nop 1\n\tv_permlane32_swap_b32 %0, %1" : "+v"(a0), "+v"(a2));
        asm("s_nop 1\n\tv_permlane32_swap_b32 %0, %1" : "+v"(a1), "+v"(a3));
        u32x4 t; t[0] = a0; t[1] = a1; t[2] = a2; t[3] = a3;
        pb[ks] = __builtin_bit_cast(bf16x8, t);
      }

      // ---- O^T += V^T P^T
      __builtin_amdgcn_s_setprio(1);
#pragma unroll
      for (int dblk = 0; dblk < 2; ++dblk) {
        const char* Vb = VsCur + (dblk * 32 + ql) * 128;
#pragma unroll
        for (int ks = 0; ks < 2; ++ks) {
          bf16x8 vf = *(const bf16x8*)(Vb + (((th * 4 + ks * 2 + h) ^ (ql & 7)) << 4));
          o[dblk] = __builtin_amdgcn_mfma_f32_32x32x16_bf16(vf, pb[ks], o[dblk], 0, 0, 0);
        }
      }
      __builtin_amdgcn_s_setprio(0);

      // ---- counted-wait barrier: K[t+1] landed (2 newer loads in flight)
      if (tid < 256) asm volatile("s_waitcnt vmcnt(2)" ::: "memory");
      else           asm volatile("s_waitcnt lgkmcnt(0)" ::: "memory");
      __builtin_amdgcn_s_barrier();
      __builtin_amdgcn_sched_barrier(0);
    }
  }

  // drain wrapped tail K loads before reusing SM for the epilogue
  if (tid < 256) asm volatile("s_waitcnt vmcnt(0)" ::: "memory");
  __syncthreads();

  // ---- cross-half l sum (lane l <-> l^32 hold complementary t-subsets)
  float px = l_r, py = l_r;
  asm("s_nop 1\n\tv_permlane32_swap_b32 %0, %1" : "+v"(px), "+v"(py));
  float lw = l_r + (h ? px : py);

  // ---- epilogue combine across t-halves (wave pairs w, w+4 share qb)
  if (th == 1) {
    char* reg = SM + qb * 8320;
#pragma unroll
    for (int dblk = 0; dblk < 2; ++dblk)
#pragma unroll
      for (int r = 0; r < 16; ++r) {
        int dl = dblk * 32 + (r & 3) + 8 * (r >> 2) + 4 * h;
        *(float*)(reg + dl * 128 + ql * 4) = o[dblk][r];
      }
    if (h == 0) *(float*)(reg + 8192 + ql * 4) = lw;
  }
  __syncthreads();
  if (th == 0) {
    const char* reg = SM + qb * 8320;
#pragma unroll
    for (int dblk = 0; dblk < 2; ++dblk)
#pragma unroll
      for (int r = 0; r < 16; ++r) {
        int dl = dblk * 32 + (r & 3) + 8 * (r >> 2) + 4 * h;
        o[dblk][r] += *(const float*)(reg + dl * 128 + ql * 4);
      }
    float inv = 1.0f / (lw + *(const float*)(reg + 8192 + ql * 4));
    long row = rowbase + q0w + ql;
#pragma unroll
    for (int dblk = 0; dblk < 2; ++dblk)
#pragma unroll
      for (int m = 0; m < 4; ++m) {
        ushort4 st;
        st.x = f2b(o[dblk][4 * m + 0] * inv);
        st.y = f2b(o[dblk][4 * m + 1] * inv);
        st.z = f2b(o[dblk][4 * m + 2] * inv);
        st.w = f2b(o[dblk][4 * m + 3] * inv);
        *(ushort4*)(outb + row * 1024 + qcol + dblk * 32 + 8 * m + 4 * h) = st;
      }
  }
}

// ---------------------------------------------------------------- launch
extern "C" void kernel_launch(void* const* d_in, const int* in_sizes, int n_in,
                              void* d_out, int out_size, void* d_ws, size_t ws_size,
                              hipStream_t stream) {
  const float* x     = (const float*)d_in[0];  // [2,2048,1024]
  const float* w_qkv = (const float*)d_in[1];  // [3072,1024]
  const float* w_out = (const float*)d_in[2];  // [1024,1024]
  float* out = (float*)d_out;                  // [2,2048,1024] fp32

  char* ws = (char*)d_ws;
  u16* xb    = (u16*)(ws);                     //  8 MB
  u16* wqkvb = (u16*)(ws + 8388608);           //  6 MB (w_out cast follows contiguously)
  u16* woutb = (u16*)(ws + 14680064);          //  2 MB
  u16* qkv   = (u16*)(ws + 16777216);          // 24 MB
  u16* attn  = (u16*)(ws + 41943040);          //  8 MB

  cast_x<<<1024, 256, 0, stream>>>(x, xb, 4096 * 1024 / 4);
  cast_w<<<1024, 256, 0, stream>>>(w_qkv, w_out, wqkvb);

  gemm_bt<true ><<<dim3(24, 32), 256, 0, stream>>>(xb, wqkvb, qkv, 4096, 3072, 1024);
  attn_fwd<<<dim3(16, 16, 2), 512, 0, stream>>>(qkv, attn);
  gemm_bt<false><<<dim3(8, 32), 256, 0, stream>>>(attn, woutb, out, 4096, 1024, 1024);
}

// Round 8
// 118.600 us; speedup vs baseline: 2.1978x; 1.9881x over previous
//
#include <hip/hip_runtime.h>
#include <stdint.h>

typedef unsigned short u16;
typedef __bf16 bf16x8 __attribute__((ext_vector_type(8)));
typedef float f32x4 __attribute__((ext_vector_type(4)));
typedef float f32x16 __attribute__((ext_vector_type(16)));
typedef unsigned u32x4 __attribute__((ext_vector_type(4)));

#define DEVI __device__ __forceinline__

typedef __attribute__((address_space(1))) void gvoid;
typedef __attribute__((address_space(3))) void lvoid;

DEVI u16 f2b(float f) {
  unsigned x = __builtin_bit_cast(unsigned, f);
  return (u16)((x + 0x7fffu + ((x >> 16) & 1u)) >> 16);
}

DEVI float exp2g(float x) { return __builtin_amdgcn_exp2f(x); }

DEVI void gload_lds16(const void* g, void* l) {
  __builtin_amdgcn_global_load_lds((gvoid*)g, (lvoid*)l, 16, 0, 0);
}

// ---------------------------------------------------------------- cast kernels
// Q rows of w_qkv get scale 0.125 * log2(e): folds the attention 1/8 scale AND
// the exp->exp2 conversion into the QKV GEMM.
#define QSCALE 0.18033688011112042f

__global__ void cast_x(const float* __restrict__ in, u16* __restrict__ out, int n4) {
  int i = blockIdx.x * 256 + threadIdx.x;
  int stride = gridDim.x * 256;
  for (; i < n4; i += stride) {
    float4 v = ((const float4*)in)[i];
    ushort4 o;
    o.x = f2b(v.x); o.y = f2b(v.y); o.z = f2b(v.z); o.w = f2b(v.w);
    ((ushort4*)out)[i] = o;
  }
}

__global__ void cast_w(const float* __restrict__ wqkv, const float* __restrict__ wout,
                       u16* __restrict__ outb) {
  int i = blockIdx.x * 256 + threadIdx.x;
  int stride = gridDim.x * 256;
  for (; i < 1048576; i += stride) {
    const float* src = (i < 786432) ? wqkv + 4 * (long)i : wout + 4 * (long)(i - 786432);
    float4 v = *(const float4*)src;
    if (i < 262144) { v.x *= QSCALE; v.y *= QSCALE; v.z *= QSCALE; v.w *= QSCALE; }
    ushort4 o;
    o.x = f2b(v.x); o.y = f2b(v.y); o.z = f2b(v.z); o.w = f2b(v.w);
    ((ushort4*)outb)[i] = o;
  }
}

// ---------------------------------------------------------------- GEMM C = A * B^T
template<bool BF16OUT>
__global__ __launch_bounds__(256)
void gemm_bt(const u16* __restrict__ A, const u16* __restrict__ B, void* __restrict__ Cv,
             int M, int N, int K) {
  __shared__ u16 lA[128 * 64];
  __shared__ u16 lB[128 * 64];
  const int tid = threadIdx.x;
  const int lane = tid & 63;
  const int lr = lane & 15;
  const int lg = lane >> 4;
  const int wid = tid >> 6;
  const long bm = (long)blockIdx.y * 128;
  const long bn = (long)blockIdx.x * 128;
  const int wr = (wid >> 1) * 64;
  const int wc = (wid & 1) * 64;

  f32x4 acc[4][4];
#pragma unroll
  for (int i = 0; i < 4; ++i)
#pragma unroll
    for (int j = 0; j < 4; ++j)
      acc[i][j] = (f32x4){0.f, 0.f, 0.f, 0.f};

  for (int k0 = 0; k0 < K; k0 += 64) {
#pragma unroll
    for (int q = 0; q < 4; ++q) {
      int bi = tid + q * 256;
      int row = bi >> 3;
      int col = ((bi & 7) ^ (row & 7)) * 8;
      gload_lds16(A + (bm + row) * (long)K + k0 + col, (char*)lA + bi * 16);
    }
#pragma unroll
    for (int q = 0; q < 4; ++q) {
      int bi = tid + q * 256;
      int row = bi >> 3;
      int col = ((bi & 7) ^ (row & 7)) * 8;
      gload_lds16(B + (bn + row) * (long)K + k0 + col, (char*)lB + bi * 16);
    }
    __syncthreads();
#pragma unroll
    for (int kk = 0; kk < 2; ++kk) {
      bf16x8 af[4], bfr[4];
      int kb = kk * 4 + lg;
#pragma unroll
      for (int mi = 0; mi < 4; ++mi) {
        int row = wr + mi * 16 + lr;
        af[mi] = *(const bf16x8*)((const char*)lA + row * 128 + ((kb ^ (row & 7)) << 4));
      }
#pragma unroll
      for (int ni = 0; ni < 4; ++ni) {
        int row = wc + ni * 16 + lr;
        bfr[ni] = *(const bf16x8*)((const char*)lB + row * 128 + ((kb ^ (row & 7)) << 4));
      }
#pragma unroll
      for (int mi = 0; mi < 4; ++mi)
#pragma unroll
        for (int ni = 0; ni < 4; ++ni)
          acc[mi][ni] = __builtin_amdgcn_mfma_f32_16x16x32_bf16(af[mi], bfr[ni], acc[mi][ni], 0, 0, 0);
    }
    __syncthreads();
  }
#pragma unroll
  for (int mi = 0; mi < 4; ++mi)
#pragma unroll
    for (int ni = 0; ni < 4; ++ni)
#pragma unroll
      for (int r = 0; r < 4; ++r) {
        long row = bm + wr + mi * 16 + lg * 4 + r;
        long col = bn + wc + ni * 16 + lr;
        float v = acc[mi][ni][r];
        if (BF16OUT) ((u16*)Cv)[row * (long)N + col] = f2b(v);
        else         ((float*)Cv)[row * (long)N + col] = v;
      }
}

// ---------------------------------------------------------------- V transpose
// vT[(b*16+h)][d][t] = qkv[b*2048+t][2048 + h*64 + d].  64t x 64d tile per block.
__global__ __launch_bounds__(256)
void transpose_v(const u16* __restrict__ qkv, u16* __restrict__ vT) {
  __shared__ u16 T[64][72];          // 144B rows: 16B-aligned, banks spread
  const int tid = threadIdx.x;
  const int t0 = blockIdx.x * 64;
  const int h  = blockIdx.y;
  const int b  = blockIdx.z;
  const int r  = tid >> 2;           // 0..63
  const int c0 = (tid & 3) * 16;     // 0..48

  const u16* src = qkv + ((long)b * 2048 + t0 + r) * 3072 + 2048 + h * 64 + c0;
  uint4 a0 = *(const uint4*)src;
  uint4 a1 = *(const uint4*)(src + 8);
  *(uint4*)&T[r][c0] = a0;
  *(uint4*)&T[r][c0 + 8] = a1;
  __syncthreads();

  // write vT row d = r, t range [t0 + c0, +16)
  u16 buf[16];
#pragma unroll
  for (int j = 0; j < 16; ++j) buf[j] = T[c0 + j][r];
  u16* dst = vT + ((long)b * 16 + h) * 131072 + r * 2048 + t0 + c0;
  *(uint4*)dst = *(const uint4*)&buf[0];
  *(uint4*)(dst + 8) = *(const uint4*)&buf[8];
}

// ---------------------------------------------------------------- flash attention v7
// v4 math (32x32x16 swapped MFMA, skip-max exp2 softmax, in-register P via
// permlane32_swap). Staging: BOTH K and V^T via global_load_lds (V from the
// pre-transposed vT buffer) -> zero staging VGPRs, uniform wave role (fixes
// v5/v6 scratch spill). Depth-2 prefetch, ring-4 LDS buffers, counted
// s_waitcnt vmcnt(2) + raw barrier per tile (never vmcnt(0) in-loop).
__global__ __launch_bounds__(512, 4)
void attn_fwd(const u16* __restrict__ qkv, const u16* __restrict__ vT,
              u16* __restrict__ outb) {
  __shared__ char SM[65536];   // K bufs 4 x 8KB @0; V bufs 4 x 8KB @32768

  const int tid = threadIdx.x;
  const int lane = tid & 63;
  const int wid = tid >> 6;
  const int ql = lane & 31;
  const int h  = lane >> 5;
  const int th = wid >> 2;     // t-half: waves 0-3 -> t 0..31, waves 4-7 -> 32..63
  const int qb = wid & 3;
  const int qt = blockIdx.x;
  const int hd = blockIdx.y;
  const int b  = blockIdx.z;

  const long rowbase = (long)b * 2048;
  const int qcol = hd * 64;
  const int kcol = 1024 + hd * 64;
  const int TSK = 64 * 3072;   // K elements per t-tile
  const long vhb = ((long)b * 16 + hd) * 131072;

  const int q0w = qt * 128 + qb * 32;
  bf16x8 qf[4];
  {
    const u16* qp = qkv + (rowbase + q0w + ql) * 3072 + qcol + h * 8;
#pragma unroll
    for (int dblk = 0; dblk < 4; ++dblk)
      qf[dblk] = *(const bf16x8*)(qp + dblk * 16);
  }

  float l_r = 0.f;
  f32x16 o[2];
#pragma unroll
  for (int d = 0; d < 2; ++d)
#pragma unroll
    for (int r = 0; r < 16; ++r) o[d][r] = 0.f;

  // staging: chunk bi = tid (512 x 16B = 8KB per tile each for K and V)
  const int rk = tid >> 3;                       // K: row t / V: row d  (0..63)
  const int ck = ((tid & 7) ^ (rk & 7)) * 8;     // pre-swizzled chunk col
  const int dstb = tid * 16;
  const u16* kp = qkv + (rowbase + rk) * 3072 + kcol + ck;
  const u16* vp = vT + vhb + rk * 2048 + ck;     // t-offset ck within tile

  // ---- prologue: stage tiles 0,1
  gload_lds16(kp, SM + dstb);                 gload_lds16(vp, SM + 32768 + dstb);
  gload_lds16(kp + TSK, SM + 8192 + dstb);    gload_lds16(vp + 64, SM + 40960 + dstb);
  kp += 2 * TSK; vp += 128;
  asm volatile("s_waitcnt vmcnt(2)" ::: "memory");
  __builtin_amdgcn_s_barrier();
  __builtin_amdgcn_sched_barrier(0);

  // ---- main loop: 8 outer x 4 unrolled = 32 tiles
  for (int tt = 0; tt < 8; ++tt) {
#pragma unroll
    for (int I = 0; I < 4; ++I) {
      char* KsCur = SM + I * 8192;
      char* KsNxt = SM + ((I + 2) & 3) * 8192;
      char* VsCur = SM + 32768 + I * 8192;
      char* VsNxt = SM + 32768 + ((I + 2) & 3) * 8192;

      // issue K[t+2], V[t+2] (tail overreads land in dead ring slots)
      gload_lds16(kp, KsNxt + dstb);  kp += TSK;
      gload_lds16(vp, VsNxt + dstb);  vp += 64;

      // ---- S^T = K Q^T
      f32x16 s;
#pragma unroll
      for (int r = 0; r < 16; ++r) s[r] = 0.f;
      const char* Kb = KsCur + (th * 32 + ql) * 128;
      __builtin_amdgcn_s_setprio(1);
#pragma unroll
      for (int kd = 0; kd < 4; ++kd) {
        bf16x8 kf = *(const bf16x8*)(Kb + (((kd * 2 + h) ^ (ql & 7)) << 4));
        s = __builtin_amdgcn_mfma_f32_32x32x16_bf16(kf, qf[kd], s, 0, 0, 0);
      }
      __builtin_amdgcn_s_setprio(0);

      // ---- softmax (shift=0): p = exp2(s) in place
#pragma unroll
      for (int r = 0; r < 16; ++r) s[r] = exp2g(s[r]);
      l_r += (((s[0] + s[1]) + (s[2] + s[3])) + ((s[4] + s[5]) + (s[6] + s[7])))
           + (((s[8] + s[9]) + (s[10] + s[11])) + ((s[12] + s[13]) + (s[14] + s[15])));

      unsigned w[8];
#pragma unroll
      for (int m = 0; m < 8; ++m)
        asm("v_cvt_pk_bf16_f32 %0, %1, %2" : "=v"(w[m]) : "v"(s[2 * m]), "v"(s[2 * m + 1]));

      bf16x8 pb[2];
#pragma unroll
      for (int ks = 0; ks < 2; ++ks) {
        unsigned a0 = w[4 * ks],     a2 = w[4 * ks + 2];
        unsigned a1 = w[4 * ks + 1], a3 = w[4 * ks + 3];
        asm("s_nop 1\n\tv_permlane32_swap_b32 %0, %1" : "+v"(a0), "+v"(a2));
        asm("s_nop 1\n\tv_permlane32_swap_b32 %0, %1" : "+v"(a1), "+v"(a3));
        u32x4 t; t[0] = a0; t[1] = a1; t[2] = a2; t[3] = a3;
        pb[ks] = __builtin_bit_cast(bf16x8, t);
      }

      // ---- O^T += V^T P^T
      __builtin_amdgcn_s_setprio(1);
#pragma unroll
      for (int dblk = 0; dblk < 2; ++dblk) {
        const char* Vb = VsCur + (dblk * 32 + ql) * 128;
#pragma unroll
        for (int ks = 0; ks < 2; ++ks) {
          bf16x8 vf = *(const bf16x8*)(Vb + (((th * 4 + ks * 2 + h) ^ (ql & 7)) << 4));
          o[dblk] = __builtin_amdgcn_mfma_f32_32x32x16_bf16(vf, pb[ks], o[dblk], 0, 0, 0);
        }
      }
      __builtin_amdgcn_s_setprio(0);

      // ---- counted-wait barrier: K/V[t+1] landed (2 newer loads in flight)
      asm volatile("s_waitcnt vmcnt(2)" ::: "memory");
      __builtin_amdgcn_s_barrier();
      __builtin_amdgcn_sched_barrier(0);
    }
  }

  // drain wrapped tail loads before reusing SM for the epilogue
  asm volatile("s_waitcnt vmcnt(0)" ::: "memory");
  __syncthreads();

  // ---- cross-half l sum (lane l <-> l^32 hold complementary t-subsets)
  float px = l_r, py = l_r;
  asm("s_nop 1\n\tv_permlane32_swap_b32 %0, %1" : "+v"(px), "+v"(py));
  float lw = l_r + (h ? px : py);

  // ---- epilogue combine across t-halves (wave pairs w, w+4 share qb)
  if (th == 1) {
    char* reg = SM + qb * 8320;
#pragma unroll
    for (int dblk = 0; dblk < 2; ++dblk)
#pragma unroll
      for (int r = 0; r < 16; ++r) {
        int dl = dblk * 32 + (r & 3) + 8 * (r >> 2) + 4 * h;
        *(float*)(reg + dl * 128 + ql * 4) = o[dblk][r];
      }
    if (h == 0) *(float*)(reg + 8192 + ql * 4) = lw;
  }
  __syncthreads();
  if (th == 0) {
    const char* reg = SM + qb * 8320;
#pragma unroll
    for (int dblk = 0; dblk < 2; ++dblk)
#pragma unroll
      for (int r = 0; r < 16; ++r) {
        int dl = dblk * 32 + (r & 3) + 8 * (r >> 2) + 4 * h;
        o[dblk][r] += *(const float*)(reg + dl * 128 + ql * 4);
      }
    float inv = 1.0f / (lw + *(const float*)(reg + 8192 + ql * 4));
    long row = rowbase + q0w + ql;
#pragma unroll
    for (int dblk = 0; dblk < 2; ++dblk)
#pragma unroll
      for (int m = 0; m < 4; ++m) {
        ushort4 st;
        st.x = f2b(o[dblk][4 * m + 0] * inv);
        st.y = f2b(o[dblk][4 * m + 1] * inv);
        st.z = f2b(o[dblk][4 * m + 2] * inv);
        st.w = f2b(o[dblk][4 * m + 3] * inv);
        *(ushort4*)(outb + row * 1024 + qcol + dblk * 32 + 8 * m + 4 * h) = st;
      }
  }
}

// ---------------------------------------------------------------- launch
extern "C" void kernel_launch(void* const* d_in, const int* in_sizes, int n_in,
                              void* d_out, int out_size, void* d_ws, size_t ws_size,
                              hipStream_t stream) {
  const float* x     = (const float*)d_in[0];  // [2,2048,1024]
  const float* w_qkv = (const float*)d_in[1];  // [3072,1024]
  const float* w_out = (const float*)d_in[2];  // [1024,1024]
  float* out = (float*)d_out;                  // [2,2048,1024] fp32

  char* ws = (char*)d_ws;
  u16* xb    = (u16*)(ws);                     //  8 MB (dead after gemm1)
  u16* vT    = (u16*)(ws);                     //  8 MB, reuses xb region
  u16* wqkvb = (u16*)(ws + 8388608);           //  6 MB (w_out cast follows)
  u16* woutb = (u16*)(ws + 14680064);          //  2 MB
  u16* qkv   = (u16*)(ws + 16777216);          // 24 MB
  u16* attn  = (u16*)(ws + 41943040);          //  8 MB

  cast_x<<<1024, 256, 0, stream>>>(x, xb, 4096 * 1024 / 4);
  cast_w<<<1024, 256, 0, stream>>>(w_qkv, w_out, wqkvb);

  gemm_bt<true ><<<dim3(24, 32), 256, 0, stream>>>(xb, wqkvb, qkv, 4096, 3072, 1024);
  transpose_v<<<dim3(32, 16, 2), 256, 0, stream>>>(qkv, vT);
  attn_fwd<<<dim3(16, 16, 2), 512, 0, stream>>>(qkv, vT, attn);
  gemm_bt<false><<<dim3(8, 32), 256, 0, stream>>>(attn, woutb, out, 4096, 1024, 1024);
}